// Round 8
// baseline (470.017 us; speedup 1.0000x reference)
//
#include <hip/hip_runtime.h>
#include <hip/hip_bf16.h>

// OddOneOutNet forward: B=1024, N=5, H=W=64, D=24, NK=6, META=16.
// Inputs fp32, output fp32, math fp32.
// Kernel A (unchanged from R7): per-panel TinyCNN, 40 KB LDS, 4 blocks/CU.
// Kernel B (R8): wave-per-row head, 2 rows per 128-thr block, ALL weights
//   except s1_w staged into LDS once per block (fixes divergent global
//   weight loads -- each per-lane-o load instr touched up to 40 cache lines).

// ---------------------------------------------------------------------------
// Kernel A. lds[10000] floats:
//   phase 1: inBuf[66*66]=4356 at offset 0
//   phase 2: h1[8][32][34]=8704 at offset 0 (aliases inBuf), h2[12][18][18] at 8704
// ---------------------------------------------------------------------------
__global__ __launch_bounds__(256, 4)
void cnn_panel_kernel(const float* __restrict__ xin,   // [BN,64,64]
                      const float* __restrict__ c1w, const float* __restrict__ c1b,
                      const float* __restrict__ c2w, const float* __restrict__ c2b,
                      const float* __restrict__ c3w, const float* __restrict__ c3b,
                      float* __restrict__ pooled)      // [BN,16] (ws)
{
    __shared__ float lds[10000];
    float* const inBuf = lds;
    float* const h1    = lds;          // aliases inBuf in phase 2
    float* const h2    = lds + 8704;

    const int tid = threadIdx.x;
    const int img = blockIdx.x;

    for (int i = tid; i < 66 * 66; i += 256) inBuf[i] = 0.0f;
    __syncthreads();

    {
        const float4* xv = (const float4*)(xin + (size_t)img * 4096);
        for (int i = tid; i < 1024; i += 256) {
            float4 u = xv[i];
            int base = i << 2;
            int y = base >> 6, x = base & 63;
            float* dst = &inBuf[(y + 1) * 66 + (x + 1)];
            dst[0] = u.x; dst[1] = u.y; dst[2] = u.z; dst[3] = u.w;
        }
    }
    __syncthreads();

    float c1out[4][8];
    #pragma unroll
    for (int p = 0; p < 4; ++p) {
        int pos = tid + (p << 8);
        int py = pos >> 5, px = pos & 31;
        float patch[4][4];
        #pragma unroll
        for (int dy = 0; dy < 4; ++dy)
            #pragma unroll
            for (int dx = 0; dx < 4; ++dx)
                patch[dy][dx] = inBuf[(2 * py + dy) * 66 + (2 * px + dx)];
        #pragma unroll
        for (int c = 0; c < 8; ++c) {
            float bb = c1b[c];
            float m = -1e30f;
            #pragma unroll
            for (int ay = 0; ay < 2; ++ay)
                #pragma unroll
                for (int ax = 0; ax < 2; ++ax) {
                    float acc = bb;
                    #pragma unroll
                    for (int ky = 0; ky < 3; ++ky)
                        #pragma unroll
                        for (int kx = 0; kx < 3; ++kx)
                            acc += patch[ay + ky][ax + kx] * c1w[c * 9 + ky * 3 + kx];
                    m = fmaxf(m, acc);
                }
            c1out[p][c] = fmaxf(m, 0.0f);
        }
    }
    __syncthreads();

    #pragma unroll
    for (int p = 0; p < 4; ++p) {
        int pos = tid + (p << 8);
        int py = pos >> 5, px = pos & 31;
        #pragma unroll
        for (int c = 0; c < 8; ++c)
            h1[c * 1088 + py * 34 + (px + 1)] = c1out[p][c];
    }
    for (int i = tid; i < 512; i += 256) {
        int c = i >> 6, rest = i & 63;
        int y = rest >> 1, side = rest & 1;
        h1[c * 1088 + y * 34 + side * 33] = 0.0f;
    }
    for (int i = tid; i < 12 * 18 * 18; i += 256) h2[i] = 0.0f;
    __syncthreads();

    {
        int py = tid >> 4, px = tid & 15;
        float acc[12][4];
        #pragma unroll
        for (int c = 0; c < 12; ++c) {
            float bb = c2b[c];
            acc[c][0] = bb; acc[c][1] = bb; acc[c][2] = bb; acc[c][3] = bb;
        }
        for (int ci = 0; ci < 8; ++ci) {
            float patch[4][4];
            #pragma unroll
            for (int dy = 0; dy < 4; ++dy) {
                int r = 2 * py - 1 + dy;
                bool okr = (r >= 0) && (r < 32);
                const float* row = &h1[ci * 1088 + r * 34 + 2 * px];
                #pragma unroll
                for (int dx = 0; dx < 4; ++dx)
                    patch[dy][dx] = okr ? row[dx] : 0.0f;
            }
            #pragma unroll
            for (int c = 0; c < 12; ++c) {
                const float* wp = &c2w[(c * 8 + ci) * 9];
                #pragma unroll
                for (int ay = 0; ay < 2; ++ay)
                    #pragma unroll
                    for (int ax = 0; ax < 2; ++ax) {
                        float a = acc[c][ay * 2 + ax];
                        #pragma unroll
                        for (int ky = 0; ky < 3; ++ky)
                            #pragma unroll
                            for (int kx = 0; kx < 3; ++kx)
                                a += patch[ay + ky][ax + kx] * wp[ky * 3 + kx];
                        acc[c][ay * 2 + ax] = a;
                    }
            }
        }
        #pragma unroll
        for (int c = 0; c < 12; ++c) {
            float m = fmaxf(fmaxf(acc[c][0], acc[c][1]), fmaxf(acc[c][2], acc[c][3]));
            h2[c * 324 + (py + 1) * 18 + (px + 1)] = fmaxf(m, 0.0f);
        }
    }
    __syncthreads();

    {
        int y = tid >> 4, x = tid & 15;
        float acc[16];
        #pragma unroll
        for (int c = 0; c < 16; ++c) acc[c] = c3b[c];
        for (int ci = 0; ci < 12; ++ci) {
            float patch[3][3];
            #pragma unroll
            for (int dy = 0; dy < 3; ++dy)
                #pragma unroll
                for (int dx = 0; dx < 3; ++dx)
                    patch[dy][dx] = h2[ci * 324 + (y + dy) * 18 + (x + dx)];
            #pragma unroll
            for (int c = 0; c < 16; ++c) {
                const float* wp = &c3w[(c * 12 + ci) * 9];
                float a = acc[c];
                #pragma unroll
                for (int ky = 0; ky < 3; ++ky)
                    #pragma unroll
                    for (int kx = 0; kx < 3; ++kx)
                        a += patch[ky][kx] * wp[ky * 3 + kx];
                acc[c] = a;
            }
        }
        float* red = h1;
        int lane = tid & 63, wave = tid >> 6;
        #pragma unroll
        for (int c = 0; c < 16; ++c) {
            float v = fmaxf(acc[c], 0.0f);
            v += __shfl_down(v, 32);
            v += __shfl_down(v, 16);
            v += __shfl_down(v, 8);
            v += __shfl_down(v, 4);
            v += __shfl_down(v, 2);
            v += __shfl_down(v, 1);
            if (lane == 0) red[c * 4 + wave] = v;
        }
        __syncthreads();
        if (tid < 16) {
            float s = red[tid * 4] + red[tid * 4 + 1] + red[tid * 4 + 2] + red[tid * 4 + 3];
            pooled[(size_t)img * 16 + tid] = s * (1.0f / 256.0f);
        }
    }
}

// ---------------------------------------------------------------------------
// Kernel B: head. 128-thread blocks = 2 waves = 2 rows. All weights except
// s1_w staged in LDS (W arena, 8199 floats). One barrier after staging, then
// wave-synchronous. LDS = 32,796 + 2*15,520 = 63,836 B.
// ---------------------------------------------------------------------------
struct RowS {
    float ph[5][16], mt[5][16];
    float zc[5][20], zmh[5][12], zm[5][12];
    float p1h[5][24], h0[5][24];
    float archl[5][6], q[5][6];
    float center[5][24], coord[5][24], x0[5][24];
    float qkv[5][72];
    float attn[2][5][5];
    float amix[5][24], aout[5][24], x1[5][24];
    float ffh[5][48], ff2o[5][24], hset[5][24], mo[5][24];
    float pq[20], pdist[20];
    float relh[20][10], relo[20][10];
    float rmean[5][10], rmax[5][10];
    float sfeat[5][146];
    float s1h[5][40];
};

// W-arena offsets (floats)
#define W_ENCW   0
#define W_ENCB   320
#define W_M1W    340
#define W_M1B    532
#define W_M2W    544
#define W_M2B    688
#define W_P1W    700
#define W_P1B    1468
#define W_P2W    1492
#define W_P2B    2068
#define W_CEN    2092
#define W_ARCW   2236
#define W_ARCB   2380
#define W_INW    2386
#define W_INB    4114
#define W_OUTW   4186
#define W_OUTB   4762
#define W_LN1G   4786
#define W_LN1B   4810
#define W_FF1W   4834
#define W_FF1B   5986
#define W_FF2W   6034
#define W_FF2B   7186
#define W_LN2G   7210
#define W_LN2B   7234
#define W_R1W    7258
#define W_R1B    7998
#define W_R2W    8008
#define W_R2B    8108
#define W_S1B    8118
#define W_S2W    8158
#define W_S2B    8198
#define W_TOTAL  8199

__global__ __launch_bounds__(128)
void head_kernel(const float* __restrict__ pooled,    // [B*5,16]
                 const float* __restrict__ meta,      // [B,5,16]
                 const float* __restrict__ enc_fc_w, const float* __restrict__ enc_fc_b,
                 const float* __restrict__ m1_w, const float* __restrict__ m1_b,
                 const float* __restrict__ m2_w, const float* __restrict__ m2_b,
                 const float* __restrict__ p1_w, const float* __restrict__ p1_b,
                 const float* __restrict__ p2_w, const float* __restrict__ p2_b,
                 const float* __restrict__ centers,
                 const float* __restrict__ arch_w, const float* __restrict__ arch_b,
                 const float* __restrict__ in_proj_w, const float* __restrict__ in_proj_b,
                 const float* __restrict__ out_proj_w, const float* __restrict__ out_proj_b,
                 const float* __restrict__ ln1_g, const float* __restrict__ ln1_b,
                 const float* __restrict__ ff1_w, const float* __restrict__ ff1_b,
                 const float* __restrict__ ff2_w, const float* __restrict__ ff2_b,
                 const float* __restrict__ ln2_g, const float* __restrict__ ln2_b,
                 const float* __restrict__ rel1_w, const float* __restrict__ rel1_b,
                 const float* __restrict__ rel2_w, const float* __restrict__ rel2_b,
                 const float* __restrict__ s1_w, const float* __restrict__ s1_b,
                 const float* __restrict__ s2_w, const float* __restrict__ s2_b,
                 float* __restrict__ out, int q_off, int Bb)
{
    __shared__ float W[W_TOTAL];
    __shared__ RowS S[2];

    const int t = threadIdx.x;

    // ---- stage weights (coalesced, once per block) ----
    #define CPW(off, src, n) for (int i = t; i < (n); i += 128) W[(off) + i] = (src)[i];
    CPW(W_ENCW, enc_fc_w, 320)  CPW(W_ENCB, enc_fc_b, 20)
    CPW(W_M1W,  m1_w,  192)     CPW(W_M1B,  m1_b,  12)
    CPW(W_M2W,  m2_w,  144)     CPW(W_M2B,  m2_b,  12)
    CPW(W_P1W,  p1_w,  768)     CPW(W_P1B,  p1_b,  24)
    CPW(W_P2W,  p2_w,  576)     CPW(W_P2B,  p2_b,  24)
    CPW(W_CEN,  centers, 144)
    CPW(W_ARCW, arch_w, 144)    CPW(W_ARCB, arch_b, 6)
    CPW(W_INW,  in_proj_w, 1728) CPW(W_INB, in_proj_b, 72)
    CPW(W_OUTW, out_proj_w, 576) CPW(W_OUTB, out_proj_b, 24)
    CPW(W_LN1G, ln1_g, 24)      CPW(W_LN1B, ln1_b, 24)
    CPW(W_FF1W, ff1_w, 1152)    CPW(W_FF1B, ff1_b, 48)
    CPW(W_FF2W, ff2_w, 1152)    CPW(W_FF2B, ff2_b, 24)
    CPW(W_LN2G, ln2_g, 24)      CPW(W_LN2B, ln2_b, 24)
    CPW(W_R1W,  rel1_w, 740)    CPW(W_R1B,  rel1_b, 10)
    CPW(W_R2W,  rel2_w, 100)    CPW(W_R2B,  rel2_b, 10)
    CPW(W_S1B,  s1_b, 40)
    CPW(W_S2W,  s2_w, 40)       CPW(W_S2B,  s2_b, 1)
    #undef CPW
    __syncthreads();

    const int wid  = t >> 6;
    const int lane = t & 63;
    const int row  = blockIdx.x * 2 + wid;
    if (row >= Bb) return;

    RowS& H = S[wid];

    for (int i = lane; i < 80; i += 64) ((float*)H.ph)[i] = pooled[(size_t)row * 80 + i];
    for (int i = lane; i < 80; i += 64) ((float*)H.mt)[i] = meta[(size_t)row * 80 + i];

    for (int idx = lane; idx < 100; idx += 64) {
        int n = idx / 20, o = idx % 20;
        float a = W[W_ENCB + o];
        #pragma unroll
        for (int k = 0; k < 16; ++k) a += H.ph[n][k] * W[W_ENCW + o * 16 + k];
        H.zc[n][o] = a;
    }
    for (int idx = lane; idx < 60; idx += 64) {
        int n = idx / 12, o = idx % 12;
        float a = W[W_M1B + o];
        #pragma unroll
        for (int k = 0; k < 16; ++k) a += H.mt[n][k] * W[W_M1W + o * 16 + k];
        H.zmh[n][o] = fmaxf(a, 0.0f);
    }
    for (int idx = lane; idx < 60; idx += 64) {
        int n = idx / 12, o = idx % 12;
        float a = W[W_M2B + o];
        #pragma unroll
        for (int k = 0; k < 12; ++k) a += H.zmh[n][k] * W[W_M2W + o * 12 + k];
        H.zm[n][o] = a;
    }
    for (int idx = lane; idx < 120; idx += 64) {
        int n = idx / 24, o = idx % 24;
        float a = W[W_P1B + o];
        #pragma unroll
        for (int k = 0; k < 20; ++k) a += H.zc[n][k] * W[W_P1W + o * 32 + k];
        #pragma unroll
        for (int k = 0; k < 12; ++k) a += H.zm[n][k] * W[W_P1W + o * 32 + 20 + k];
        H.p1h[n][o] = fmaxf(a, 0.0f);
    }
    for (int idx = lane; idx < 120; idx += 64) {
        int n = idx / 24, o = idx % 24;
        float a = W[W_P2B + o];
        #pragma unroll
        for (int k = 0; k < 24; ++k) a += H.p1h[n][k] * W[W_P2W + o * 24 + k];
        H.h0[n][o] = a;
    }
    for (int idx = lane; idx < 30; idx += 64) {
        int n = idx / 6, o = idx % 6;
        float a = W[W_ARCB + o];
        #pragma unroll
        for (int k = 0; k < 24; ++k) a += H.h0[n][k] * W[W_ARCW + o * 24 + k];
        H.archl[n][o] = a;
    }
    if (lane < 5) {
        int n = lane;
        float m = H.archl[n][0];
        #pragma unroll
        for (int k = 1; k < 6; ++k) m = fmaxf(m, H.archl[n][k]);
        float e[6], s = 0.0f;
        #pragma unroll
        for (int k = 0; k < 6; ++k) { e[k] = __expf(H.archl[n][k] - m); s += e[k]; }
        float inv = 1.0f / s;
        #pragma unroll
        for (int k = 0; k < 6; ++k) H.q[n][k] = e[k] * inv;
    }
    for (int idx = lane; idx < 120; idx += 64) {
        int n = idx / 24, d = idx % 24;
        float a = 0.0f;
        #pragma unroll
        for (int k = 0; k < 6; ++k) a += H.q[n][k] * W[W_CEN + k * 24 + d];
        H.center[n][d] = a;
        H.coord[n][d] = H.h0[n][d] - a;
        H.x0[n][d] = H.h0[n][d] + a;
    }
    for (int idx = lane; idx < 360; idx += 64) {
        int n = idx / 72, o = idx % 72;
        float a = W[W_INB + o];
        #pragma unroll
        for (int k = 0; k < 24; ++k) a += H.x0[n][k] * W[W_INW + o * 24 + k];
        H.qkv[n][o] = a;
    }
    if (lane < 10) {
        int h = lane / 5, i = lane % 5;
        const float scale = 0.28867513459481287f;  // 1/sqrt(12)
        float sc[5], m = -1e30f;
        for (int j = 0; j < 5; ++j) {
            float a = 0.0f;
            #pragma unroll
            for (int d = 0; d < 12; ++d) a += H.qkv[i][h * 12 + d] * H.qkv[j][24 + h * 12 + d];
            sc[j] = a * scale;
            m = fmaxf(m, sc[j]);
        }
        float s = 0.0f;
        #pragma unroll
        for (int j = 0; j < 5; ++j) { sc[j] = __expf(sc[j] - m); s += sc[j]; }
        float inv = 1.0f / s;
        #pragma unroll
        for (int j = 0; j < 5; ++j) H.attn[h][i][j] = sc[j] * inv;
    }
    for (int idx = lane; idx < 120; idx += 64) {
        int i = idx / 24, o = idx % 24;
        int h = o / 12, d = o % 12;
        float a = 0.0f;
        #pragma unroll
        for (int j = 0; j < 5; ++j) a += H.attn[h][i][j] * H.qkv[j][48 + h * 12 + d];
        H.amix[i][o] = a;
    }
    for (int idx = lane; idx < 120; idx += 64) {
        int n = idx / 24, o = idx % 24;
        float a = W[W_OUTB + o];
        #pragma unroll
        for (int k = 0; k < 24; ++k) a += H.amix[n][k] * W[W_OUTW + o * 24 + k];
        H.aout[n][o] = H.x0[n][o] + a;
    }
    if (lane < 5) {
        int n = lane;
        float m = 0.0f;
        #pragma unroll
        for (int k = 0; k < 24; ++k) m += H.aout[n][k];
        m *= (1.0f / 24.0f);
        float v = 0.0f;
        #pragma unroll
        for (int k = 0; k < 24; ++k) { float d = H.aout[n][k] - m; v += d * d; }
        v *= (1.0f / 24.0f);
        float inv = 1.0f / sqrtf(v + 1e-5f);
        #pragma unroll
        for (int k = 0; k < 24; ++k)
            H.x1[n][k] = (H.aout[n][k] - m) * inv * W[W_LN1G + k] + W[W_LN1B + k];
    }
    for (int idx = lane; idx < 240; idx += 64) {
        int n = idx / 48, o = idx % 48;
        float a = W[W_FF1B + o];
        #pragma unroll
        for (int k = 0; k < 24; ++k) a += H.x1[n][k] * W[W_FF1W + o * 24 + k];
        H.ffh[n][o] = fmaxf(a, 0.0f);
    }
    for (int idx = lane; idx < 120; idx += 64) {
        int n = idx / 24, o = idx % 24;
        float a = W[W_FF2B + o];
        #pragma unroll
        for (int k = 0; k < 48; ++k) a += H.ffh[n][k] * W[W_FF2W + o * 48 + k];
        H.ff2o[n][o] = H.x1[n][o] + a;
    }
    if (lane < 5) {
        int n = lane;
        float m = 0.0f;
        #pragma unroll
        for (int k = 0; k < 24; ++k) m += H.ff2o[n][k];
        m *= (1.0f / 24.0f);
        float v = 0.0f;
        #pragma unroll
        for (int k = 0; k < 24; ++k) { float d = H.ff2o[n][k] - m; v += d * d; }
        v *= (1.0f / 24.0f);
        float inv = 1.0f / sqrtf(v + 1e-5f);
        #pragma unroll
        for (int k = 0; k < 24; ++k)
            H.hset[n][k] = (H.ff2o[n][k] - m) * inv * W[W_LN2G + k] + W[W_LN2B + k];
    }
    for (int idx = lane; idx < 120; idx += 64) {
        int n = idx / 24, d = idx % 24;
        float s = H.hset[0][d] + H.hset[1][d] + H.hset[2][d] + H.hset[3][d] + H.hset[4][d];
        H.mo[n][d] = (s - H.hset[n][d]) * 0.25f;
    }
    if (lane < 20) {
        int i = lane / 4, jj = lane % 4;
        int j = jj + (jj >= i ? 1 : 0);
        float qo = 0.0f;
        #pragma unroll
        for (int k = 0; k < 6; ++k) qo += H.q[i][k] * H.q[j][k];
        H.pq[lane] = qo;
        float d2 = 0.0f;
        #pragma unroll
        for (int k = 0; k < 24; ++k) { float d = H.coord[i][k] - H.coord[j][k]; d2 += d * d; }
        H.pdist[lane] = (d2 > 0.0f) ? sqrtf(d2) : 0.0f;
    }
    for (int idx = lane; idx < 200; idx += 64) {
        int p = idx / 10, c = idx % 10;
        int i = p / 4, jj = p % 4;
        int j = jj + (jj >= i ? 1 : 0);
        float a = W[W_R1B + c];
        const int wr = W_R1W + c * 74;
        #pragma unroll
        for (int k = 0; k < 24; ++k) a += H.hset[i][k] * W[wr + k];
        #pragma unroll
        for (int k = 0; k < 24; ++k) a += H.hset[j][k] * W[wr + 24 + k];
        #pragma unroll
        for (int k = 0; k < 24; ++k) a += fabsf(H.coord[i][k] - H.coord[j][k]) * W[wr + 48 + k];
        a += H.pq[p] * W[wr + 72];
        a += H.pdist[p] * W[wr + 73];
        H.relh[p][c] = fmaxf(a, 0.0f);
    }
    for (int idx = lane; idx < 200; idx += 64) {
        int p = idx / 10, c = idx % 10;
        float a = W[W_R2B + c];
        #pragma unroll
        for (int k = 0; k < 10; ++k) a += H.relh[p][k] * W[W_R2W + c * 10 + k];
        H.relo[p][c] = fmaxf(a, 0.0f);
    }
    for (int idx = lane; idx < 50; idx += 64) {
        int i = idx / 10, c = idx % 10;
        float s = 0.0f, m = -1e30f;
        #pragma unroll
        for (int jj = 0; jj < 4; ++jj) {
            float v = H.relo[i * 4 + jj][c];
            s += v; m = fmaxf(m, v);
        }
        H.rmean[i][c] = s * 0.25f;
        H.rmax[i][c] = m;
    }
    for (int idx = lane; idx < 730; idx += 64) {
        int n = idx / 146, k = idx % 146;
        float v;
        if (k < 24)       v = H.h0[n][k];
        else if (k < 48)  v = H.hset[n][k - 24];
        else if (k < 72)  v = H.center[n][k - 48];
        else if (k < 96)  v = H.coord[n][k - 72];
        else if (k < 120) v = fabsf(H.hset[n][k - 96] - H.mo[n][k - 96]);
        else if (k < 130) v = H.rmean[n][k - 120];
        else if (k < 140) v = H.rmax[n][k - 130];
        else              v = H.q[n][k - 140];
        H.sfeat[n][k] = v;
    }
    // s1: n-fastest lane map -> 13 distinct weight rows per load instr (was 40)
    for (int idx = lane; idx < 200; idx += 64) {
        int n = idx % 5, o = idx / 5;
        float a = W[W_S1B + o];
        #pragma unroll 8
        for (int k = 0; k < 146; ++k) a += H.sfeat[n][k] * s1_w[o * 146 + k];
        H.s1h[n][o] = fmaxf(a, 0.0f);
    }
    if (lane < 5) {
        int n = lane;
        float a = W[W_S2B];
        #pragma unroll
        for (int k = 0; k < 40; ++k) a += H.s1h[n][k] * W[W_S2W + k];
        out[(size_t)row * 5 + n] = a;
    }
    if (lane < 30) {
        out[q_off + (size_t)row * 30 + lane] = H.q[lane / 6][lane % 6];
    }
}

extern "C" void kernel_launch(void* const* d_in, const int* in_sizes, int n_in,
                              void* d_out, int out_size, void* d_ws, size_t ws_size,
                              hipStream_t stream) {
    const int BN = in_sizes[0] / (64 * 64);   // B*5
    const int Bb = BN / 5;                    // B

    float* pooled = (float*)d_ws;             // [BN][16] fp32

    cnn_panel_kernel<<<BN, 256, 0, stream>>>(
        (const float*)d_in[0],
        (const float*)d_in[2], (const float*)d_in[3],
        (const float*)d_in[4], (const float*)d_in[5],
        (const float*)d_in[6], (const float*)d_in[7],
        pooled);

    head_kernel<<<(Bb + 1) / 2, 128, 0, stream>>>(
        pooled, (const float*)d_in[1],
        (const float*)d_in[8], (const float*)d_in[9],
        (const float*)d_in[10], (const float*)d_in[11],
        (const float*)d_in[12], (const float*)d_in[13],
        (const float*)d_in[14], (const float*)d_in[15],
        (const float*)d_in[16], (const float*)d_in[17],
        (const float*)d_in[18],
        (const float*)d_in[19], (const float*)d_in[20],
        (const float*)d_in[21], (const float*)d_in[22],
        (const float*)d_in[23], (const float*)d_in[24],
        (const float*)d_in[25], (const float*)d_in[26],
        (const float*)d_in[27], (const float*)d_in[28],
        (const float*)d_in[29], (const float*)d_in[30],
        (const float*)d_in[31], (const float*)d_in[32],
        (const float*)d_in[33], (const float*)d_in[34],
        (const float*)d_in[35], (const float*)d_in[36],
        (const float*)d_in[37], (const float*)d_in[38],
        (const float*)d_in[39], (const float*)d_in[40],
        (float*)d_out, BN, Bb);
}